// Round 4
// baseline (309.035 us; speedup 1.0000x reference)
//
#include <hip/hip_runtime.h>
#include <hip/hip_bf16.h>

#define BATCH   8
#define C_DIM   512
#define HWD     56
#define NPIX    3136   // 56*56
#define PW      14
#define PP      196    // 14*14
#define M_TOT   588    // 3*196
#define BM_ROWS 4704   // 8*588
#define BM_PAD  4736   // padded to 37*128
#define HEADS   8
#define HD      64
#define N_SEQ   3136
#define SM_SCALE 0.125f

typedef __attribute__((ext_vector_type(8))) short bf16x8;
typedef __attribute__((ext_vector_type(4))) float f32x4;

__device__ __forceinline__ short f2bs(float f) {
    __hip_bfloat16 h = __float2bfloat16(f);
    return *reinterpret_cast<short*>(&h);
}
__device__ __forceinline__ unsigned pkbf(float lo, float hi) {
    __hip_bfloat162 t = __float22bfloat162_rn(make_float2(lo, hi));
    return *reinterpret_cast<unsigned*>(&t);
}

// async 16B global->LDS copy (m97 pattern, wave-uniform LDS base).
__device__ __forceinline__ void gl_lds16(const void* g, void* l) {
    __builtin_amdgcn_global_load_lds(
        (const __attribute__((address_space(1))) void*)g,
        (__attribute__((address_space(3))) void*)l, 16, 0, 0);
}

// ---------------------------------------------------------------------------
// Kernel A: the three depthwise branches. One block per (b,c) plane.
// ---------------------------------------------------------------------------
__global__ __launch_bounds__(256) void k_branches(
    const float* __restrict__ x,
    const float* __restrict__ w1a, const float* __restrict__ b1a,
    const float* __restrict__ w1b, const float* __restrict__ b1b,
    const float* __restrict__ w2,  const float* __restrict__ b2,
    const float* __restrict__ w3,  const float* __restrict__ b3,
    float* __restrict__ l_pre)
{
    __shared__ float xs[NPIX];
    __shared__ float y1s[HWD * PW];
    __shared__ float pools[PP];
    const int c = blockIdx.x, b = blockIdx.y, tid = threadIdx.x;
    const float* xp = x + ((size_t)(b * C_DIM + c)) * NPIX;
    for (int i = tid; i < NPIX / 4; i += 256)
        ((float4*)xs)[i] = ((const float4*)xp)[i];
    __syncthreads();

    const float wa0 = w1a[c*4+0], wa1 = w1a[c*4+1], wa2 = w1a[c*4+2], wa3 = w1a[c*4+3];
    const float ba = b1a[c];
    for (int i = tid; i < HWD * PW; i += 256) {
        int h = i / PW, w = i % PW;
        const float* r = xs + h * HWD + w * 4;
        float v = ba + r[0]*wa0 + r[1]*wa1 + r[2]*wa2 + r[3]*wa3;
        y1s[i] = fmaxf(v, 0.f);
    }
    if (tid < PP) {
        int h = tid / PW, w = tid % PW;
        float s = 0.f;
        #pragma unroll
        for (int r = 0; r < 4; ++r) {
            const float* rr = xs + (h*4 + r) * HWD + w * 4;
            s += rr[0] + rr[1] + rr[2] + rr[3];
        }
        pools[tid] = s * (1.f / 16.f);
    }
    __syncthreads();

    if (tid < PP) {
        int h = tid / PW, w = tid % PW;
        float* lp = l_pre + ((size_t)(b * C_DIM + c)) * M_TOT;
        float v1 = b1b[c];
        v1 += y1s[(h*4+0)*PW + w] * w1b[c*4+0];
        v1 += y1s[(h*4+1)*PW + w] * w1b[c*4+1];
        v1 += y1s[(h*4+2)*PW + w] * w1b[c*4+2];
        v1 += y1s[(h*4+3)*PW + w] * w1b[c*4+3];
        lp[tid] = fmaxf(v1, 0.f);
        float v2 = b2[c];
        #pragma unroll
        for (int r = 0; r < 4; ++r)
            #pragma unroll
            for (int s2 = 0; s2 < 4; ++s2)
                v2 += xs[(h*4+r)*HWD + w*4 + s2] * w2[c*16 + r*4 + s2];
        lp[PP + tid] = fmaxf(v2, 0.f);
        float v3 = b3[c];
        #pragma unroll
        for (int dh = -1; dh <= 1; ++dh)
            #pragma unroll
            for (int dw = -1; dw <= 1; ++dw) {
                int hh = h + dh, ww = w + dw;
                if (hh >= 0 && hh < PW && ww >= 0 && ww < PW)
                    v3 += pools[hh*PW + ww] * w3[c*9 + (dh+1)*3 + (dw+1)];
            }
        lp[2*PP + tid] = fmaxf(v3, 0.f);
    }
}

// ---------------------------------------------------------------------------
// Kernel B: LayerNorm stats over C for each (b,m).
// ---------------------------------------------------------------------------
__global__ __launch_bounds__(256) void k_stats(
    const float* __restrict__ l_pre, float2* __restrict__ stats)
{
    __shared__ float ssum[4][64];
    __shared__ float ssq[4][64];
    const int tid = threadIdx.x;
    const int ml = tid & 63, cg = tid >> 6;
    const int b = blockIdx.y;
    const int m = blockIdx.x * 64 + ml;
    float s = 0.f, q = 0.f;
    if (m < M_TOT) {
        const float* base = l_pre + ((size_t)b * C_DIM + cg * 128) * M_TOT + m;
        for (int c = 0; c < 128; ++c) {
            float v = base[(size_t)c * M_TOT];
            s += v; q += v * v;
        }
    }
    ssum[cg][ml] = s; ssq[cg][ml] = q;
    __syncthreads();
    if (tid < 64 && blockIdx.x * 64 + tid < M_TOT) {
        float ts = ssum[0][tid] + ssum[1][tid] + ssum[2][tid] + ssum[3][tid];
        float tq = ssq[0][tid] + ssq[1][tid] + ssq[2][tid] + ssq[3][tid];
        float mu = ts * (1.f / 512.f);
        float var = tq * (1.f / 512.f) - mu * mu;
        stats[(size_t)b * M_TOT + blockIdx.x * 64 + tid] =
            make_float2(mu, rsqrtf(var + 1e-5f));
    }
}

// ---------------------------------------------------------------------------
// Kernel W: weights fp32 -> bf16.
// ---------------------------------------------------------------------------
__global__ __launch_bounds__(256) void k_wconv(
    const float* __restrict__ Wq, const float* __restrict__ Wkv,
    short* __restrict__ Wqb, short* __restrict__ Wkvb)
{
    int i = (blockIdx.x * 256 + threadIdx.x) * 4;
    if (i < 262144) {
        float4 v = *(const float4*)(Wq + i);
        short o[4] = {f2bs(v.x), f2bs(v.y), f2bs(v.z), f2bs(v.w)};
        *(short4*)(Wqb + i) = *(short4*)o;
    } else {
        int j = i - 262144;
        float4 v = *(const float4*)(Wkv + j);
        short o[4] = {f2bs(v.x), f2bs(v.y), f2bs(v.z), f2bs(v.w)};
        *(short4*)(Wkvb + j) = *(short4*)o;
    }
}

// ---------------------------------------------------------------------------
// Kernel X: x [B,C,N] fp32 -> Xb [B*N, C] bf16 (transpose + convert).
// ---------------------------------------------------------------------------
__global__ __launch_bounds__(256) void k_xpose(
    const float* __restrict__ x, short* __restrict__ Xb)
{
    __shared__ float sx[64][68];
    const int tid = threadIdx.x;
    const int n0 = blockIdx.x * 64, c0 = blockIdx.y * 64, b = blockIdx.z;
    #pragma unroll
    for (int it = 0; it < 4; ++it) {
        int idx = tid + it * 256;
        int cr = idx >> 4, n4 = (idx & 15) * 4;
        float4 v = *(const float4*)(x + ((size_t)(b * C_DIM + c0 + cr)) * NPIX + n0 + n4);
        *(float4*)&sx[cr][n4] = v;
    }
    __syncthreads();
    #pragma unroll
    for (int p = 0; p < 2; ++p) {
        int idx = tid + p * 256;
        int nr = idx >> 3, cg = (idx & 7) * 8;
        short ov[8];
        #pragma unroll
        for (int e = 0; e < 8; ++e) ov[e] = f2bs(sx[cg + e][nr]);
        *(float4*)&Xb[((size_t)(b * NPIX + n0 + nr)) * C_DIM + c0 + cg] = *(float4*)ov;
    }
}

// ---------------------------------------------------------------------------
// Kernel L: LN(l_pre) transposed -> Lb [BM_PAD, C] bf16.
// ---------------------------------------------------------------------------
__global__ __launch_bounds__(256) void k_lnt(
    const float* __restrict__ l_pre, const float2* __restrict__ stats,
    const float* __restrict__ gamma, const float* __restrict__ beta,
    short* __restrict__ Lb)
{
    __shared__ float sx[64][68];
    const int tid = threadIdx.x;
    const int m0 = blockIdx.x * 64, c0 = blockIdx.y * 64, b = blockIdx.z;
    #pragma unroll
    for (int it = 0; it < 4; ++it) {
        int idx = tid + it * 256;
        int cr = idx >> 4, m4 = (idx & 15) * 4;
        float4 v = {0.f, 0.f, 0.f, 0.f};
        if (m0 + m4 < M_TOT)
            v = *(const float4*)(l_pre + ((size_t)(b * C_DIM + c0 + cr)) * M_TOT + m0 + m4);
        *(float4*)&sx[cr][m4] = v;
    }
    __syncthreads();
    #pragma unroll
    for (int p = 0; p < 2; ++p) {
        int idx = tid + p * 256;
        int mr = idx >> 3, cg = (idx & 7) * 8;
        int m = m0 + mr;
        float mu = 0.f, rstd = 0.f;
        if (m < M_TOT) {
            float2 st = stats[(size_t)b * M_TOT + m];
            mu = st.x; rstd = st.y;
        }
        short ov[8];
        #pragma unroll
        for (int e = 0; e < 8; ++e) {
            int c = c0 + cg + e;
            ov[e] = f2bs((sx[cg + e][mr] - mu) * rstd * gamma[c] + beta[c]);
        }
        if (m < M_TOT)
            *(float4*)&Lb[((size_t)(b * M_TOT + m)) * C_DIM + c0 + cg] = *(float4*)ov;
    }
}

// ---------------------------------------------------------------------------
// Kernel G0: q GEMM (rows = B*N, cols 512 -> Qb [B,h,N,d]).
// 128x128 tile, BK=64, global_load_lds staging.
// ---------------------------------------------------------------------------
__global__ __launch_bounds__(256) void k_gemm_q(
    const short* __restrict__ A, const short* __restrict__ Bw,
    const float* __restrict__ bias, short* __restrict__ Qb)
{
    __shared__ short As[128 * 64];
    __shared__ short Bs[128 * 64];
    const int tid = threadIdx.x;
    const int lane = tid & 63, w = tid >> 6;
    const int l15 = lane & 15, quad = lane >> 4;
    const int wr = w & 1, wc = w >> 1;
    const int row0 = blockIdx.x * 128, col0 = blockIdx.y * 128;
    const int lr8 = lane >> 3, lc8 = (lane & 7) * 8;

    f32x4 acc[4][4] = {};

    for (int c0 = 0; c0 < 512; c0 += 64) {
        __syncthreads();
        #pragma unroll
        for (int it = 0; it < 4; ++it) {
            int r = w * 32 + it * 8;
            gl_lds16(A  + (size_t)(row0 + r + lr8) * 512 + c0 + lc8, &As[r * 64]);
            gl_lds16(Bw + (size_t)(col0 + r + lr8) * 512 + c0 + lc8, &Bs[r * 64]);
        }
        __syncthreads();
        #pragma unroll
        for (int ks = 0; ks < 2; ++ks) {
            bf16x8 af[4], bf[4];
            #pragma unroll
            for (int t = 0; t < 4; ++t) {
                af[t] = *(const bf16x8*)&As[(wr*64 + t*16 + l15)*64 + ks*32 + quad*8];
                bf[t] = *(const bf16x8*)&Bs[(wc*64 + t*16 + l15)*64 + ks*32 + quad*8];
            }
            #pragma unroll
            for (int nt = 0; nt < 4; ++nt)
                #pragma unroll
                for (int mt = 0; mt < 4; ++mt)
                    acc[nt][mt] = __builtin_amdgcn_mfma_f32_16x16x32_bf16(
                        af[nt], bf[mt], acc[nt][mt], 0, 0, 0);
        }
    }

    #pragma unroll
    for (int nt = 0; nt < 4; ++nt) {
        int row_t = row0 + wr * 64 + nt * 16 + quad * 4;
        #pragma unroll
        for (int mt = 0; mt < 4; ++mt) {
            int col = col0 + wc * 64 + mt * 16 + l15;
            float bv = bias[col];
            int h = col >> 6, d = col & 63;
            #pragma unroll
            for (int r = 0; r < 4; ++r) {
                int row_g = row_t + r;
                int b = row_g / N_SEQ;
                int n = row_g - b * N_SEQ;
                Qb[(((size_t)(b * HEADS + h)) * N_SEQ + n) * HD + d] =
                    f2bs(acc[nt][mt][r] + bv);
            }
        }
    }
}

// ---------------------------------------------------------------------------
// Kernel G1: kv GEMM (rows = B*M padded, cols 1024 -> Kb / Vt).
// ---------------------------------------------------------------------------
__global__ __launch_bounds__(256) void k_gemm_kv(
    const short* __restrict__ A, const short* __restrict__ Bw,
    const float* __restrict__ bias,
    short* __restrict__ Kb, short* __restrict__ Vt)
{
    __shared__ short As[128 * 64];
    __shared__ short Bs[128 * 64];
    const int tid = threadIdx.x;
    const int lane = tid & 63, w = tid >> 6;
    const int l15 = lane & 15, quad = lane >> 4;
    const int wr = w & 1, wc = w >> 1;
    const int row0 = blockIdx.x * 128, col0 = blockIdx.y * 128;
    const int lr8 = lane >> 3, lc8 = (lane & 7) * 8;

    f32x4 acc[4][4] = {};

    for (int c0 = 0; c0 < 512; c0 += 64) {
        __syncthreads();
        #pragma unroll
        for (int it = 0; it < 4; ++it) {
            int r = w * 32 + it * 8;
            gl_lds16(A  + (size_t)(row0 + r + lr8) * 512 + c0 + lc8, &As[r * 64]);
            gl_lds16(Bw + (size_t)(col0 + r + lr8) * 512 + c0 + lc8, &Bs[r * 64]);
        }
        __syncthreads();
        #pragma unroll
        for (int ks = 0; ks < 2; ++ks) {
            bf16x8 af[4], bf[4];
            #pragma unroll
            for (int t = 0; t < 4; ++t) {
                af[t] = *(const bf16x8*)&As[(wr*64 + t*16 + l15)*64 + ks*32 + quad*8];
                bf[t] = *(const bf16x8*)&Bs[(wc*64 + t*16 + l15)*64 + ks*32 + quad*8];
            }
            #pragma unroll
            for (int nt = 0; nt < 4; ++nt)
                #pragma unroll
                for (int mt = 0; mt < 4; ++mt)
                    acc[nt][mt] = __builtin_amdgcn_mfma_f32_16x16x32_bf16(
                        af[nt], bf[mt], acc[nt][mt], 0, 0, 0);
        }
    }

    #pragma unroll
    for (int nt = 0; nt < 4; ++nt) {
        int row_t = row0 + wr * 64 + nt * 16 + quad * 4;
        #pragma unroll
        for (int mt = 0; mt < 4; ++mt) {
            int col = col0 + wc * 64 + mt * 16 + l15;
            float bv = bias[col];
            #pragma unroll
            for (int r = 0; r < 4; ++r) {
                int row_g = row_t + r;
                float v = acc[nt][mt][r] + bv;
                if (row_g < BM_ROWS) {
                    int b = row_g / M_TOT;
                    int m = row_g - b * M_TOT;
                    if (col < 512) {
                        int h = col >> 6, d = col & 63;
                        Kb[(((size_t)(b * HEADS + h)) * M_TOT + m) * HD + d] = f2bs(v);
                    } else {
                        int jj = col - 512, h = jj >> 6, d = jj & 63;
                        Vt[(((size_t)(b * HEADS + h)) * HD + d) * M_TOT + m] = f2bs(v);
                    }
                }
            }
        }
    }
}

// ---------------------------------------------------------------------------
// Kernel E: MFMA attention, operand-swapped (S^T and O^T).
// Each lane owns ONE Q-row (i = l15): row-sums are per-lane scalars; the
// P C-layout -> B-operand transform is done in-register with shfl_xor
// (quad exchange), no LDS round trip, no bank conflicts. O^T is transposed
// once per block via an LDS buffer aliased over Ks/Vs (dead after the last
// barrier), keeping coalesced float4 output stores.
// ---------------------------------------------------------------------------
__global__ __launch_bounds__(256) void k_attn(
    const short* __restrict__ Qb, const short* __restrict__ Kb,
    const short* __restrict__ Vt, float* __restrict__ out)
{
    __shared__ __align__(16) short smem[3 * 64 * 72];   // Qs | Ks | Vs
    short* Qs = smem;
    short* Ks = smem + 64 * 72;
    short* Vs = smem + 2 * 64 * 72;
    float* Os = (float*)(smem + 64 * 72);   // epilogue alias (18432B >= 64*68*4)

    const int tid = threadIdx.x;
    const int lane = tid & 63, w = tid >> 6;
    const int l15 = lane & 15, quad = lane >> 4;
    const int n0 = blockIdx.x * 64, h = blockIdx.y, b = blockIdx.z;
    const size_t bh = (size_t)(b * HEADS + h);
    const size_t qbase = (bh * N_SEQ + n0) * HD;
    const size_t kbase = bh * M_TOT * HD;
    const size_t vbase = bh * (size_t)HD * M_TOT;

    #pragma unroll
    for (int it = 0; it < 2; ++it) {
        int idx = tid + it * 256;
        int row = idx >> 3, seg = idx & 7;
        *(float4*)&Qs[row * 72 + seg * 8] =
            *(const float4*)(Qb + qbase + (size_t)row * HD + seg * 8);
    }

    f32x4 oacc[4] = {};   // oacc[dt][r] = O[i=l15][d = dt*16 + quad*4 + r]
    float rs = 0.f;       // per-lane partial row sum, row i=l15

    __syncthreads();
    bf16x8 qf[2];   // B-operand: Q^T[d][i]; lane n=i=l15, k=d=quad*8+jj
    #pragma unroll
    for (int ks = 0; ks < 2; ++ks)
        qf[ks] = *(const bf16x8*)&Qs[(w * 16 + l15) * 72 + ks * 32 + quad * 8];

    for (int jc0 = 0; jc0 < M_TOT; jc0 += 64) {
        // ---- stage K chunk (rows j, cols d) and V chunk (rows d, cols j)
        if (jc0 + 64 <= M_TOT) {
            #pragma unroll
            for (int it = 0; it < 2; ++it) {
                int idx = tid + it * 256;
                int row = idx >> 3, seg = idx & 7;
                *(float4*)&Ks[row * 72 + seg * 8] =
                    *(const float4*)(Kb + kbase + (size_t)(jc0 + row) * HD + seg * 8);
                *(float4*)&Vs[row * 72 + seg * 8] =
                    *(const float4*)(Vt + vbase + (size_t)row * M_TOT + jc0 + seg * 8);
            }
        } else {
            #pragma unroll
            for (int it = 0; it < 2; ++it) {
                int idx = tid + it * 256;
                int row = idx >> 3, seg = idx & 7;
                int jg = jc0 + row;
                if (jg < M_TOT) {
                    *(float4*)&Ks[row * 72 + seg * 8] =
                        *(const float4*)(Kb + kbase + (size_t)jg * HD + seg * 8);
                } else {
                    float4 z = {0.f, 0.f, 0.f, 0.f};
                    *(float4*)&Ks[row * 72 + seg * 8] = z;
                }
                #pragma unroll
                for (int t2 = 0; t2 < 8; ++t2) {
                    int jj = jc0 + seg * 8 + t2;
                    Vs[row * 72 + seg * 8 + t2] = (jj < M_TOT)
                        ? Vt[vbase + (size_t)row * M_TOT + jj] : (short)0;
                }
            }
        }
        __syncthreads();

        // ---- S^T tiles: sacc[t][r] = S[i=l15][j = jc0 + t*16 + quad*4 + r]
        f32x4 sacc[4] = {};
        #pragma unroll
        for (int t = 0; t < 4; ++t)
            #pragma unroll
            for (int ks = 0; ks < 2; ++ks) {
                bf16x8 kf = *(const bf16x8*)&Ks[(t * 16 + l15) * 72 + ks * 32 + quad * 8];
                sacc[t] = __builtin_amdgcn_mfma_f32_16x16x32_bf16(
                    kf, qf[ks], sacc[t], 0, 0, 0);
            }

        // ---- softmax: per-lane exp + scalar row-sum accumulate
        float p[4][4];
        if (jc0 + 64 <= M_TOT) {
            #pragma unroll
            for (int t = 0; t < 4; ++t)
                #pragma unroll
                for (int r = 0; r < 4; ++r) {
                    p[t][r] = __expf(sacc[t][r] * SM_SCALE);
                    rs += p[t][r];
                }
        } else {
            #pragma unroll
            for (int t = 0; t < 4; ++t)
                #pragma unroll
                for (int r = 0; r < 4; ++r) {
                    int jg = jc0 + t * 16 + quad * 4 + r;
                    float pv = (jg < M_TOT) ? __expf(sacc[t][r] * SM_SCALE) : 0.f;
                    p[t][r] = pv;
                    rs += pv;
                }
        }
        // pack to bf16 pairs: pk[t][0]=(r0,r1), pk[t][1]=(r2,r3)
        unsigned pk[4][2];
        #pragma unroll
        for (int t = 0; t < 4; ++t) {
            pk[t][0] = pkbf(p[t][0], p[t][1]);
            pk[t][1] = pkbf(p[t][2], p[t][3]);
        }

        // ---- PV: per 32-wide k-chunk, build P^T B-operand frag via quad
        // exchange (values needed live in same-l15 lanes of other quads)
        const bool c0 = (quad & 1) != 0, c1 = (quad & 2) != 0;
        #pragma unroll
        for (int kc = 0; kc < 2; ++kc) {
            const int ta = 2 * kc, tb = 2 * kc + 1;
            unsigned P0x = pk[ta][0], P0y = pk[ta][1];
            unsigned P1x = pk[tb][0], P1y = pk[tb][1];
            unsigned X0x = __shfl_xor(P0x, 16), X0y = __shfl_xor(P0y, 16);
            unsigned X1x = __shfl_xor(P1x, 16), X1y = __shfl_xor(P1y, 16);
            unsigned Y0x = __shfl_xor(P0x, 32), Y0y = __shfl_xor(P0y, 32);
            unsigned Y1x = __shfl_xor(P1x, 32), Y1y = __shfl_xor(P1y, 32);
            unsigned Z0x = __shfl_xor(X0x, 32), Z0y = __shfl_xor(X0y, 32);
            unsigned Z1x = __shfl_xor(X1x, 32), Z1y = __shfl_xor(X1y, 32);
            // srcA: q0->P0, q1->Z0, q2->Y1, q3->X1
            // srcB: q0->X0, q1->Y0, q2->Z1, q3->P1
            unsigned pv4[4];
            pv4[0] = c1 ? (c0 ? X1x : Y1x) : (c0 ? Z0x : P0x);
            pv4[1] = c1 ? (c0 ? X1y : Y1y) : (c0 ? Z0y : P0y);
            pv4[2] = c1 ? (c0 ? P1x : Z1x) : (c0 ? Y0x : X0x);
            pv4[3] = c1 ? (c0 ? P1y : Z1y) : (c0 ? Y0y : X0y);
            bf16x8 pf;
            __builtin_memcpy(&pf, pv4, 16);
            #pragma unroll
            for (int dt = 0; dt < 4; ++dt) {
                bf16x8 vf = *(const bf16x8*)&Vs[(dt * 16 + l15) * 72 + kc * 32 + quad * 8];
                oacc[dt] = __builtin_amdgcn_mfma_f32_16x16x32_bf16(
                    vf, pf, oacc[dt], 0, 0, 0);
            }
        }
        __syncthreads();
    }

    // ---- epilogue: finish row sum (cross-quad), normalize, transpose, store
    rs += __shfl_xor(rs, 16);
    rs += __shfl_xor(rs, 32);
    float inv = 1.f / rs;
    #pragma unroll
    for (int dt = 0; dt < 4; ++dt)
        #pragma unroll
        for (int r = 0; r < 4; ++r)
            Os[(w * 16 + l15) * 68 + dt * 16 + quad * 4 + r] = oacc[dt][r] * inv;
    __syncthreads();
    #pragma unroll
    for (int it = 0; it < 4; ++it) {
        int row = (tid >> 4) + it * 16;
        int c4 = (tid & 15) * 4;
        float4 v = *(const float4*)&Os[row * 68 + c4];
        *(float4*)&out[((size_t)b * N_SEQ + n0 + row) * C_DIM + h * HD + c4] = v;
    }
}

// ---------------------------------------------------------------------------
extern "C" void kernel_launch(void* const* d_in, const int* in_sizes, int n_in,
                              void* d_out, int out_size, void* d_ws, size_t ws_size,
                              hipStream_t stream) {
    const float* x     = (const float*)d_in[0];
    const float* Wq    = (const float*)d_in[1];
    const float* bq    = (const float*)d_in[2];
    const float* Wkv   = (const float*)d_in[3];
    const float* bkv   = (const float*)d_in[4];
    const float* w1a   = (const float*)d_in[5];
    const float* b1a   = (const float*)d_in[6];
    const float* w1b   = (const float*)d_in[7];
    const float* b1b   = (const float*)d_in[8];
    const float* w2    = (const float*)d_in[9];
    const float* b2    = (const float*)d_in[10];
    const float* w3    = (const float*)d_in[11];
    const float* b3    = (const float*)d_in[12];
    const float* gamma = (const float*)d_in[13];
    const float* beta  = (const float*)d_in[14];
    float* out = (float*)d_out;

    char* ws = (char*)d_ws;
    short*  Xb    = (short*)ws;                    // 25,690,112 B (phase 1)
    float*  l_pre = (float*)ws;                    //  9,633,792 B (aliases Xb, phase 2)
    float2* stats = (float2*)(ws + 9633792);       //     37,632 B
    short*  Lb    = (short*)(ws + 9671424);        //  4,849,664 B ([4736,512])
    short*  Wqb   = (short*)(ws + 25690112);       //    524,288 B
    short*  Wkvb  = (short*)(ws + 26214400);       //  1,048,576 B
    short*  Kb    = (short*)(ws + 27262976);       //  4,816,896 B [B,h,M,d]
    short*  Vt    = (short*)(ws + 32079872);       //  4,816,896 B [B,h,d,M]
    short*  Qb    = (short*)(ws + 36896768);       // 25,690,112 B [B,h,N,d]

    k_wconv<<<768, 256, 0, stream>>>(Wq, Wkv, Wqb, Wkvb);
    k_xpose<<<dim3(49, 8, BATCH), 256, 0, stream>>>(x, Xb);
    k_gemm_q<<<dim3(196, 4), 256, 0, stream>>>(Xb, Wqb, bq, Qb);
    // Xb dead; region becomes l_pre/stats/Lb
    k_branches<<<dim3(C_DIM, BATCH), 256, 0, stream>>>(
        x, w1a, b1a, w1b, b1b, w2, b2, w3, b3, l_pre);
    k_stats<<<dim3(10, BATCH), 256, 0, stream>>>(l_pre, stats);
    k_lnt<<<dim3(10, 8, BATCH), 256, 0, stream>>>(l_pre, stats, gamma, beta, Lb);
    k_gemm_kv<<<dim3(37, 8), 256, 0, stream>>>(Lb, Wkvb, bkv, Kb, Vt);
    k_attn<<<dim3(49, HEADS, BATCH), 256, 0, stream>>>(Qb, Kb, Vt, out);
}

// Round 5
// 275.443 us; speedup vs baseline: 1.1220x; 1.1220x over previous
//
#include <hip/hip_runtime.h>
#include <hip/hip_bf16.h>

#define BATCH   8
#define C_DIM   512
#define HWD     56
#define NPIX    3136   // 56*56
#define PW      14
#define PP      196    // 14*14
#define M_TOT   588    // 3*196
#define BM_ROWS 4704   // 8*588
#define BM_PAD  4736   // padded to 37*128
#define HEADS   8
#define HD      64
#define N_SEQ   3136
#define SM_SCALE 0.125f

// attention LDS geometry
#define KS_STRIDE 68            // shorts per K row (34 words: frag reads <=2-way)
#define KS_ROWS   592           // 588 + 4 zero pad rows
#define VS_STRIDE 596           // shorts per V^T row (298 words: <=2-way)
#define ATTN_LDS_SHORTS (KS_ROWS * KS_STRIDE + 64 * VS_STRIDE)   // 78400
#define ATTN_LDS_BYTES  (ATTN_LDS_SHORTS * 2)                    // 156800

typedef __attribute__((ext_vector_type(8))) short bf16x8;
typedef __attribute__((ext_vector_type(4))) short bf16x4;
typedef __attribute__((ext_vector_type(4))) float f32x4;

__device__ __forceinline__ short f2bs(float f) {
    __hip_bfloat16 h = __float2bfloat16(f);
    return *reinterpret_cast<short*>(&h);
}
__device__ __forceinline__ unsigned pkbf(float lo, float hi) {
    __hip_bfloat162 t = __float22bfloat162_rn(make_float2(lo, hi));
    return *reinterpret_cast<unsigned*>(&t);
}

// 16x16x16 bf16 MFMA (K=16): B-operand layout k=quad*4+jj, n=l15 — matches
// the C/D layout of our S^T tiles directly (no transpose needed for PV).
__device__ __forceinline__ f32x4 mfma16(bf16x4 a, bf16x4 b, f32x4 c) {
#if __has_builtin(__builtin_amdgcn_mfma_f32_16x16x16bf16_1k)
    return __builtin_amdgcn_mfma_f32_16x16x16bf16_1k(a, b, c, 0, 0, 0);
#elif __has_builtin(__builtin_amdgcn_mfma_f32_16x16x16_bf16)
    return __builtin_amdgcn_mfma_f32_16x16x16_bf16(a, b, c, 0, 0, 0);
#else
    asm volatile("v_mfma_f32_16x16x16_bf16 %0, %1, %2, %0\n\ts_nop 7\n\ts_nop 1"
                 : "+v"(c) : "v"(a), "v"(b));
    return c;
#endif
}

// async 16B global->LDS copy (m97 pattern, wave-uniform LDS base).
__device__ __forceinline__ void gl_lds16(const void* g, void* l) {
    __builtin_amdgcn_global_load_lds(
        (const __attribute__((address_space(1))) void*)g,
        (__attribute__((address_space(3))) void*)l, 16, 0, 0);
}

// ---------------------------------------------------------------------------
// Kernel A: the three depthwise branches. One block per (b,c) plane.
// ---------------------------------------------------------------------------
__global__ __launch_bounds__(256) void k_branches(
    const float* __restrict__ x,
    const float* __restrict__ w1a, const float* __restrict__ b1a,
    const float* __restrict__ w1b, const float* __restrict__ b1b,
    const float* __restrict__ w2,  const float* __restrict__ b2,
    const float* __restrict__ w3,  const float* __restrict__ b3,
    float* __restrict__ l_pre)
{
    __shared__ float xs[NPIX];
    __shared__ float y1s[HWD * PW];
    __shared__ float pools[PP];
    const int c = blockIdx.x, b = blockIdx.y, tid = threadIdx.x;
    const float* xp = x + ((size_t)(b * C_DIM + c)) * NPIX;
    for (int i = tid; i < NPIX / 4; i += 256)
        ((float4*)xs)[i] = ((const float4*)xp)[i];
    __syncthreads();

    const float wa0 = w1a[c*4+0], wa1 = w1a[c*4+1], wa2 = w1a[c*4+2], wa3 = w1a[c*4+3];
    const float ba = b1a[c];
    for (int i = tid; i < HWD * PW; i += 256) {
        int h = i / PW, w = i % PW;
        const float* r = xs + h * HWD + w * 4;
        float v = ba + r[0]*wa0 + r[1]*wa1 + r[2]*wa2 + r[3]*wa3;
        y1s[i] = fmaxf(v, 0.f);
    }
    if (tid < PP) {
        int h = tid / PW, w = tid % PW;
        float s = 0.f;
        #pragma unroll
        for (int r = 0; r < 4; ++r) {
            const float* rr = xs + (h*4 + r) * HWD + w * 4;
            s += rr[0] + rr[1] + rr[2] + rr[3];
        }
        pools[tid] = s * (1.f / 16.f);
    }
    __syncthreads();

    if (tid < PP) {
        int h = tid / PW, w = tid % PW;
        float* lp = l_pre + ((size_t)(b * C_DIM + c)) * M_TOT;
        float v1 = b1b[c];
        v1 += y1s[(h*4+0)*PW + w] * w1b[c*4+0];
        v1 += y1s[(h*4+1)*PW + w] * w1b[c*4+1];
        v1 += y1s[(h*4+2)*PW + w] * w1b[c*4+2];
        v1 += y1s[(h*4+3)*PW + w] * w1b[c*4+3];
        lp[tid] = fmaxf(v1, 0.f);
        float v2 = b2[c];
        #pragma unroll
        for (int r = 0; r < 4; ++r)
            #pragma unroll
            for (int s2 = 0; s2 < 4; ++s2)
                v2 += xs[(h*4+r)*HWD + w*4 + s2] * w2[c*16 + r*4 + s2];
        lp[PP + tid] = fmaxf(v2, 0.f);
        float v3 = b3[c];
        #pragma unroll
        for (int dh = -1; dh <= 1; ++dh)
            #pragma unroll
            for (int dw = -1; dw <= 1; ++dw) {
                int hh = h + dh, ww = w + dw;
                if (hh >= 0 && hh < PW && ww >= 0 && ww < PW)
                    v3 += pools[hh*PW + ww] * w3[c*9 + (dh+1)*3 + (dw+1)];
            }
        lp[2*PP + tid] = fmaxf(v3, 0.f);
    }
}

// ---------------------------------------------------------------------------
// Kernel B: LayerNorm stats over C for each (b,m).
// ---------------------------------------------------------------------------
__global__ __launch_bounds__(256) void k_stats(
    const float* __restrict__ l_pre, float2* __restrict__ stats)
{
    __shared__ float ssum[4][64];
    __shared__ float ssq[4][64];
    const int tid = threadIdx.x;
    const int ml = tid & 63, cg = tid >> 6;
    const int b = blockIdx.y;
    const int m = blockIdx.x * 64 + ml;
    float s = 0.f, q = 0.f;
    if (m < M_TOT) {
        const float* base = l_pre + ((size_t)b * C_DIM + cg * 128) * M_TOT + m;
        for (int c = 0; c < 128; ++c) {
            float v = base[(size_t)c * M_TOT];
            s += v; q += v * v;
        }
    }
    ssum[cg][ml] = s; ssq[cg][ml] = q;
    __syncthreads();
    if (tid < 64 && blockIdx.x * 64 + tid < M_TOT) {
        float ts = ssum[0][tid] + ssum[1][tid] + ssum[2][tid] + ssum[3][tid];
        float tq = ssq[0][tid] + ssq[1][tid] + ssq[2][tid] + ssq[3][tid];
        float mu = ts * (1.f / 512.f);
        float var = tq * (1.f / 512.f) - mu * mu;
        stats[(size_t)b * M_TOT + blockIdx.x * 64 + tid] =
            make_float2(mu, rsqrtf(var + 1e-5f));
    }
}

// ---------------------------------------------------------------------------
// Kernel W: weights fp32 -> bf16.
// ---------------------------------------------------------------------------
__global__ __launch_bounds__(256) void k_wconv(
    const float* __restrict__ Wq, const float* __restrict__ Wkv,
    short* __restrict__ Wqb, short* __restrict__ Wkvb)
{
    int i = (blockIdx.x * 256 + threadIdx.x) * 4;
    if (i < 262144) {
        float4 v = *(const float4*)(Wq + i);
        short o[4] = {f2bs(v.x), f2bs(v.y), f2bs(v.z), f2bs(v.w)};
        *(short4*)(Wqb + i) = *(short4*)o;
    } else {
        int j = i - 262144;
        float4 v = *(const float4*)(Wkv + j);
        short o[4] = {f2bs(v.x), f2bs(v.y), f2bs(v.z), f2bs(v.w)};
        *(short4*)(Wkvb + j) = *(short4*)o;
    }
}

// ---------------------------------------------------------------------------
// Kernel X: x [B,C,N] fp32 -> Xb [B*N, C] bf16 (transpose + convert).
// ---------------------------------------------------------------------------
__global__ __launch_bounds__(256) void k_xpose(
    const float* __restrict__ x, short* __restrict__ Xb)
{
    __shared__ float sx[64][68];
    const int tid = threadIdx.x;
    const int n0 = blockIdx.x * 64, c0 = blockIdx.y * 64, b = blockIdx.z;
    #pragma unroll
    for (int it = 0; it < 4; ++it) {
        int idx = tid + it * 256;
        int cr = idx >> 4, n4 = (idx & 15) * 4;
        float4 v = *(const float4*)(x + ((size_t)(b * C_DIM + c0 + cr)) * NPIX + n0 + n4);
        *(float4*)&sx[cr][n4] = v;
    }
    __syncthreads();
    #pragma unroll
    for (int p = 0; p < 2; ++p) {
        int idx = tid + p * 256;
        int nr = idx >> 3, cg = (idx & 7) * 8;
        short ov[8];
        #pragma unroll
        for (int e = 0; e < 8; ++e) ov[e] = f2bs(sx[cg + e][nr]);
        *(float4*)&Xb[((size_t)(b * NPIX + n0 + nr)) * C_DIM + c0 + cg] = *(float4*)ov;
    }
}

// ---------------------------------------------------------------------------
// Kernel L: LN(l_pre) transposed -> Lb [BM_PAD, C] bf16.
// ---------------------------------------------------------------------------
__global__ __launch_bounds__(256) void k_lnt(
    const float* __restrict__ l_pre, const float2* __restrict__ stats,
    const float* __restrict__ gamma, const float* __restrict__ beta,
    short* __restrict__ Lb)
{
    __shared__ float sx[64][68];
    const int tid = threadIdx.x;
    const int m0 = blockIdx.x * 64, c0 = blockIdx.y * 64, b = blockIdx.z;
    #pragma unroll
    for (int it = 0; it < 4; ++it) {
        int idx = tid + it * 256;
        int cr = idx >> 4, m4 = (idx & 15) * 4;
        float4 v = {0.f, 0.f, 0.f, 0.f};
        if (m0 + m4 < M_TOT)
            v = *(const float4*)(l_pre + ((size_t)(b * C_DIM + c0 + cr)) * M_TOT + m0 + m4);
        *(float4*)&sx[cr][m4] = v;
    }
    __syncthreads();
    #pragma unroll
    for (int p = 0; p < 2; ++p) {
        int idx = tid + p * 256;
        int mr = idx >> 3, cg = (idx & 7) * 8;
        int m = m0 + mr;
        float mu = 0.f, rstd = 0.f;
        if (m < M_TOT) {
            float2 st = stats[(size_t)b * M_TOT + m];
            mu = st.x; rstd = st.y;
        }
        short ov[8];
        #pragma unroll
        for (int e = 0; e < 8; ++e) {
            int c = c0 + cg + e;
            ov[e] = f2bs((sx[cg + e][mr] - mu) * rstd * gamma[c] + beta[c]);
        }
        if (m < M_TOT)
            *(float4*)&Lb[((size_t)(b * M_TOT + m)) * C_DIM + c0 + cg] = *(float4*)ov;
    }
}

// ---------------------------------------------------------------------------
// Kernel G0: q GEMM (rows = B*N, cols 512 -> Qb [B,h,N,d]).
// ---------------------------------------------------------------------------
__global__ __launch_bounds__(256) void k_gemm_q(
    const short* __restrict__ A, const short* __restrict__ Bw,
    const float* __restrict__ bias, short* __restrict__ Qb)
{
    __shared__ short As[128 * 64];
    __shared__ short Bs[128 * 64];
    const int tid = threadIdx.x;
    const int lane = tid & 63, w = tid >> 6;
    const int l15 = lane & 15, quad = lane >> 4;
    const int wr = w & 1, wc = w >> 1;
    const int row0 = blockIdx.x * 128, col0 = blockIdx.y * 128;
    const int lr8 = lane >> 3, lc8 = (lane & 7) * 8;

    f32x4 acc[4][4] = {};

    for (int c0 = 0; c0 < 512; c0 += 64) {
        __syncthreads();
        #pragma unroll
        for (int it = 0; it < 4; ++it) {
            int r = w * 32 + it * 8;
            gl_lds16(A  + (size_t)(row0 + r + lr8) * 512 + c0 + lc8, &As[r * 64]);
            gl_lds16(Bw + (size_t)(col0 + r + lr8) * 512 + c0 + lc8, &Bs[r * 64]);
        }
        __syncthreads();
        #pragma unroll
        for (int ks = 0; ks < 2; ++ks) {
            bf16x8 af[4], bf[4];
            #pragma unroll
            for (int t = 0; t < 4; ++t) {
                af[t] = *(const bf16x8*)&As[(wr*64 + t*16 + l15)*64 + ks*32 + quad*8];
                bf[t] = *(const bf16x8*)&Bs[(wc*64 + t*16 + l15)*64 + ks*32 + quad*8];
            }
            #pragma unroll
            for (int nt = 0; nt < 4; ++nt)
                #pragma unroll
                for (int mt = 0; mt < 4; ++mt)
                    acc[nt][mt] = __builtin_amdgcn_mfma_f32_16x16x32_bf16(
                        af[nt], bf[mt], acc[nt][mt], 0, 0, 0);
        }
    }

    #pragma unroll
    for (int nt = 0; nt < 4; ++nt) {
        int row_t = row0 + wr * 64 + nt * 16 + quad * 4;
        #pragma unroll
        for (int mt = 0; mt < 4; ++mt) {
            int col = col0 + wc * 64 + mt * 16 + l15;
            float bv = bias[col];
            int h = col >> 6, d = col & 63;
            #pragma unroll
            for (int r = 0; r < 4; ++r) {
                int row_g = row_t + r;
                int b = row_g / N_SEQ;
                int n = row_g - b * N_SEQ;
                Qb[(((size_t)(b * HEADS + h)) * N_SEQ + n) * HD + d] =
                    f2bs(acc[nt][mt][r] + bv);
            }
        }
    }
}

// ---------------------------------------------------------------------------
// Kernel G1: kv GEMM (rows = B*M padded, cols 1024 -> Kb / Vt).
// ---------------------------------------------------------------------------
__global__ __launch_bounds__(256) void k_gemm_kv(
    const short* __restrict__ A, const short* __restrict__ Bw,
    const float* __restrict__ bias,
    short* __restrict__ Kb, short* __restrict__ Vt)
{
    __shared__ short As[128 * 64];
    __shared__ short Bs[128 * 64];
    const int tid = threadIdx.x;
    const int lane = tid & 63, w = tid >> 6;
    const int l15 = lane & 15, quad = lane >> 4;
    const int wr = w & 1, wc = w >> 1;
    const int row0 = blockIdx.x * 128, col0 = blockIdx.y * 128;
    const int lr8 = lane >> 3, lc8 = (lane & 7) * 8;

    f32x4 acc[4][4] = {};

    for (int c0 = 0; c0 < 512; c0 += 64) {
        __syncthreads();
        #pragma unroll
        for (int it = 0; it < 4; ++it) {
            int r = w * 32 + it * 8;
            gl_lds16(A  + (size_t)(row0 + r + lr8) * 512 + c0 + lc8, &As[r * 64]);
            gl_lds16(Bw + (size_t)(col0 + r + lr8) * 512 + c0 + lc8, &Bs[r * 64]);
        }
        __syncthreads();
        #pragma unroll
        for (int ks = 0; ks < 2; ++ks) {
            bf16x8 af[4], bf[4];
            #pragma unroll
            for (int t = 0; t < 4; ++t) {
                af[t] = *(const bf16x8*)&As[(wr*64 + t*16 + l15)*64 + ks*32 + quad*8];
                bf[t] = *(const bf16x8*)&Bs[(wc*64 + t*16 + l15)*64 + ks*32 + quad*8];
            }
            #pragma unroll
            for (int nt = 0; nt < 4; ++nt)
                #pragma unroll
                for (int mt = 0; mt < 4; ++mt)
                    acc[nt][mt] = __builtin_amdgcn_mfma_f32_16x16x32_bf16(
                        af[nt], bf[mt], acc[nt][mt], 0, 0, 0);
        }
    }

    #pragma unroll
    for (int nt = 0; nt < 4; ++nt) {
        int row_t = row0 + wr * 64 + nt * 16 + quad * 4;
        #pragma unroll
        for (int mt = 0; mt < 4; ++mt) {
            int col = col0 + wc * 64 + mt * 16 + l15;
            float bv = bias[col];
            #pragma unroll
            for (int r = 0; r < 4; ++r) {
                int row_g = row_t + r;
                float v = acc[nt][mt][r] + bv;
                if (row_g < BM_ROWS) {
                    int b = row_g / M_TOT;
                    int m = row_g - b * M_TOT;
                    if (col < 512) {
                        int h = col >> 6, d = col & 63;
                        Kb[(((size_t)(b * HEADS + h)) * M_TOT + m) * HD + d] = f2bs(v);
                    } else {
                        int jj = col - 512, h = jj >> 6, d = jj & 63;
                        Vt[(((size_t)(b * HEADS + h)) * HD + d) * M_TOT + m] = f2bs(v);
                    }
                }
            }
        }
    }
}

// ---------------------------------------------------------------------------
// Kernel E: persistent-KV MFMA attention.
// Grid = (4 n-quarters, h, b) = 256 blocks, 1024 threads (16 waves), 1/CU.
// Whole-head K (588x64) and V^T (64x588) staged ONCE into 156.8 KB dynamic
// LDS; ONE barrier; then waves run free: each wave processes pairs of 16-row
// Q strips (K/V frag reads shared across the pair). S^T = K.Q^T via
// 16x16x32 (C-layout row j=quad*4+r, col i=l15); P packs straight into the
// 16x16x16 PV B-operand (k=j=quad*4+jj, n=i=l15) — no transpose at all.
// Tail: only quad 3 of the last j-step is invalid -> wave-uniform rs mask.
// ---------------------------------------------------------------------------
__global__ __launch_bounds__(1024) void k_attn(
    const short* __restrict__ Qb, const short* __restrict__ Kb,
    const short* __restrict__ Vt, float* __restrict__ out)
{
    extern __shared__ short smem[];
    short* Ks = smem;                       // [592][68]
    short* Vs = smem + KS_ROWS * KS_STRIDE; // [64][596]

    const int tid = threadIdx.x;
    const int lane = tid & 63, w = tid >> 6;
    const int l15 = lane & 15, quad = lane >> 4;
    const int q4 = blockIdx.x, h = blockIdx.y, b = blockIdx.z;
    const size_t bh = (size_t)(b * HEADS + h);
    const size_t kbase = bh * M_TOT * HD;          // Kb [B,h,M,d]
    const size_t vbase = bh * (size_t)HD * M_TOT;  // Vt [B,h,d,M]

    // ---- stage K: 588 rows x 64 d (4704 float4 over 1024 threads)
    for (int i = tid; i < 4704; i += 1024) {
        int row = i >> 3, seg = i & 7;
        *(float4*)&Ks[row * KS_STRIDE + seg * 8] =
            *(const float4*)(Kb + kbase + (size_t)row * 64 + seg * 8);
    }
    // K zero-pad rows 588..591 (cols 0..63)
    if (tid < 256) {
        int r = tid >> 6, cc = tid & 63;
        Ks[(588 + r) * KS_STRIDE + cc] = 0;
    }
    // ---- stage V^T: 64 d-rows x 588 j (147 float2 per row, 16 thr/row)
    {
        int row = tid >> 4, tg = tid & 15;
        const short* src = Vt + vbase + (size_t)row * M_TOT;
        #pragma unroll 2
        for (int jj = tg; jj < 147; jj += 16)
            *(float2*)&Vs[row * VS_STRIDE + jj * 4] = *(const float2*)(src + jj * 4);
    }
    // V zero-pad cols 588..595
    if (tid < 512) {
        int row = tid >> 3, cc = tid & 7;
        Vs[row * VS_STRIDE + 588 + cc] = 0;
    }
    __syncthreads();   // the ONLY barrier

    // ---- per-wave double-strips: ds covers Q rows q4*784 + ds*32 .. +31
    for (int ds = w; ds < 25; ds += 16) {
        const bool sbv = (ds < 24);           // ds==24: only strip A valid
        const int nA = q4 * 784 + ds * 32 + l15;
        const int nB = sbv ? nA + 16 : nA;    // clamp (compute waste, no store)

        bf16x8 qfA[2], qfB[2];
        #pragma unroll
        for (int ks = 0; ks < 2; ++ks) {
            qfA[ks] = *(const bf16x8*)(Qb + (bh * N_SEQ + nA) * HD + ks * 32 + quad * 8);
            qfB[ks] = *(const bf16x8*)(Qb + (bh * N_SEQ + nB) * HD + ks * 32 + quad * 8);
        }

        f32x4 oaccA[4] = {}, oaccB[4] = {};
        float rsA = 0.f, rsB = 0.f;

        for (int j0 = 0; j0 < KS_ROWS; j0 += 16) {
            const short* krow = &Ks[(j0 + l15) * KS_STRIDE];
            bf16x8 kf0 = *(const bf16x8*)&krow[quad * 8];
            bf16x8 kf1 = *(const bf16x8*)&krow[32 + quad * 8];

            f32x4 sA = {}, sB = {};
            sA = __builtin_amdgcn_mfma_f32_16x16x32_bf16(kf0, qfA[0], sA, 0, 0, 0);
            sB = __builtin_amdgcn_mfma_f32_16x16x32_bf16(kf0, qfB[0], sB, 0, 0, 0);
            sA = __builtin_amdgcn_mfma_f32_16x16x32_bf16(kf1, qfA[1], sA, 0, 0, 0);
            sB = __builtin_amdgcn_mfma_f32_16x16x32_bf16(kf1, qfB[1], sB, 0, 0, 0);

            // softmax numerators; only quad 3 of the last step is j>=588
            const float msk = (j0 == 576 && quad == 3) ? 0.f : 1.f;
            float pA[4], pB[4];
            #pragma unroll
            for (int r = 0; r < 4; ++r) {
                pA[r] = __expf(sA[r] * SM_SCALE);
                pB[r] = __expf(sB[r] * SM_SCALE);
            }
            rsA += (pA[0] + pA[1] + pA[2] + pA[3]) * msk;
            rsB += (pB[0] + pB[1] + pB[2] + pB[3]) * msk;

            unsigned ua[2] = {pkbf(pA[0], pA[1]), pkbf(pA[2], pA[3])};
            unsigned ub[2] = {pkbf(pB[0], pB[1]), pkbf(pB[2], pB[3])};
            bf16x4 pbA, pbB;
            __builtin_memcpy(&pbA, ua, 8);
            __builtin_memcpy(&pbB, ub, 8);

            // PV: O^T[d][i] += V^T[d][j] P^T[j][i] (pad j: V=0 -> no effect)
            #pragma unroll
            for (int dt = 0; dt < 4; ++dt) {
                bf16x4 vf = *(const bf16x4*)&Vs[(dt * 16 + l15) * VS_STRIDE + j0 + quad * 4];
                oaccA[dt] = mfma16(vf, pbA, oaccA[dt]);
                oaccB[dt] = mfma16(vf, pbB, oaccB[dt]);
            }
        }

        // ---- epilogue: cross-quad row sums, normalize, store O^T directly
        rsA += __shfl_xor(rsA, 16); rsA += __shfl_xor(rsA, 32);
        rsB += __shfl_xor(rsB, 16); rsB += __shfl_xor(rsB, 32);
        const float invA = 1.f / rsA;
        const float invB = 1.f / rsB;
        float* orowA = out + ((size_t)b * N_SEQ + nA) * C_DIM + h * HD;
        #pragma unroll
        for (int dt = 0; dt < 4; ++dt) {
            float4 o;
            o.x = oaccA[dt][0] * invA; o.y = oaccA[dt][1] * invA;
            o.z = oaccA[dt][2] * invA; o.w = oaccA[dt][3] * invA;
            *(float4*)&orowA[dt * 16 + quad * 4] = o;
        }
        if (sbv) {
            float* orowB = out + ((size_t)b * N_SEQ + nB) * C_DIM + h * HD;
            #pragma unroll
            for (int dt = 0; dt < 4; ++dt) {
                float4 o;
                o.x = oaccB[dt][0] * invB; o.y = oaccB[dt][1] * invB;
                o.z = oaccB[dt][2] * invB; o.w = oaccB[dt][3] * invB;
                *(float4*)&orowB[dt * 16 + quad * 4] = o;
            }
        }
    }
}

// ---------------------------------------------------------------------------
extern "C" void kernel_launch(void* const* d_in, const int* in_sizes, int n_in,
                              void* d_out, int out_size, void* d_ws, size_t ws_size,
                              hipStream_t stream) {
    const float* x     = (const float*)d_in[0];
    const float* Wq    = (const float*)d_in[1];
    const float* bq    = (const float*)d_in[2];
    const float* Wkv   = (const float*)d_in[3];
    const float* bkv   = (const float*)d_in[4];
    const float* w1a   = (const float*)d_in[5];
    const float* b1a   = (const float*)d_in[6];
    const float* w1b   = (const float*)d_in[7];
    const float* b1b   = (const float*)d_in[8];
    const float* w2    = (const float*)d_in[9];
    const float* b2    = (const float*)d_in[10];
    const float* w3    = (const float*)d_in[11];
    const float* b3    = (const float*)d_in[12];
    const float* gamma = (const float*)d_in[13];
    const float* beta  = (const float*)d_in[14];
    float* out = (float*)d_out;

    char* ws = (char*)d_ws;
    short*  Xb    = (short*)ws;                    // 25,690,112 B (phase 1)
    float*  l_pre = (float*)ws;                    //  9,633,792 B (aliases Xb, phase 2)
    float2* stats = (float2*)(ws + 9633792);       //     37,632 B
    short*  Lb    = (short*)(ws + 9671424);        //  4,849,664 B ([4736,512])
    short*  Wqb   = (short*)(ws + 25690112);       //    524,288 B
    short*  Wkvb  = (short*)(ws + 26214400);       //  1,048,576 B
    short*  Kb    = (short*)(ws + 27262976);       //  4,816,896 B [B,h,M,d]
    short*  Vt    = (short*)(ws + 32079872);       //  4,816,896 B [B,h,d,M]
    short*  Qb    = (short*)(ws + 36896768);       // 25,690,112 B [B,h,N,d]

    // allow >64KB dynamic LDS for the persistent-KV attention kernel
    static bool attr_set = false;
    hipFuncSetAttribute((const void*)k_attn,
                        hipFuncAttributeMaxDynamicSharedMemorySize,
                        ATTN_LDS_BYTES);
    (void)attr_set;

    k_wconv<<<768, 256, 0, stream>>>(Wq, Wkv, Wqb, Wkvb);
    k_xpose<<<dim3(49, 8, BATCH), 256, 0, stream>>>(x, Xb);
    k_gemm_q<<<dim3(196, 4), 256, 0, stream>>>(Xb, Wqb, bq, Qb);
    // Xb dead; region becomes l_pre/stats/Lb
    k_branches<<<dim3(C_DIM, BATCH), 256, 0, stream>>>(
        x, w1a, b1a, w1b, b1b, w2, b2, w3, b3, l_pre);
    k_stats<<<dim3(10, BATCH), 256, 0, stream>>>(l_pre, stats);
    k_lnt<<<dim3(10, 8, BATCH), 256, 0, stream>>>(l_pre, stats, gamma, beta, Lb);
    k_gemm_kv<<<dim3(37, 8), 256, 0, stream>>>(Lb, Wkvb, bkv, Kb, Vt);
    k_attn<<<dim3(4, HEADS, BATCH), 1024, ATTN_LDS_BYTES, stream>>>(Qb, Kb, Vt, out);
}